// Round 16
// baseline (536.982 us; speedup 1.0000x reference)
//
#include <hip/hip_runtime.h>
#include <hip/hip_bf16.h>

#define B_  512
#define S_  196
#define D_  1024
#define A_  512
#define O_  1000
#define NROW (B_ * S_)   // 100352 = 784 * 128

typedef __attribute__((ext_vector_type(8))) __bf16 bf16x8_t;
typedef __attribute__((ext_vector_type(4))) float f32x4;
typedef __attribute__((ext_vector_type(4))) float f32x4v;

__device__ __forceinline__ unsigned short f2bf(float f) {
    union { float f; unsigned u; } v; v.f = f;
    unsigned r = v.u + 0x7FFFu + ((v.u >> 16) & 1u);   // RNE
    return (unsigned short)(r >> 16);
}
__device__ __forceinline__ unsigned pk2(float lo, float hi) {
    return (unsigned)f2bf(lo) | ((unsigned)f2bf(hi) << 16);
}
__device__ __forceinline__ float bf2f(unsigned short h) {
    union { unsigned u; float f; } v; v.u = ((unsigned)h) << 16;
    return v.f;
}

// ---- img [NROW][1024] f32 -> imgbfP fragment-packed bf16:
//      [rfrag = row/16][ks = k/32][lane][8]  where lane = (row&15) + 16*((k&31)/8)
__global__ void img2bf(const float* __restrict__ img, unsigned short* __restrict__ imgbfP) {
    size_t gid = (size_t)blockIdx.x * 256 + threadIdx.x;
    int    lane  = (int)(gid & 63);
    size_t chunk = gid >> 6;             // (rfrag*32 + ks)
    int    ks    = (int)(chunk & 31);
    size_t rfrag = chunk >> 5;
    int row = (int)(rfrag * 16 + (lane & 15));
    int k0  = ks * 32 + (lane >> 4) * 8;
    const float* src = img + (size_t)row * D_ + k0;
    f32x4v v0 = __builtin_nontemporal_load(reinterpret_cast<const f32x4v*>(src));
    f32x4v v1 = __builtin_nontemporal_load(reinterpret_cast<const f32x4v*>(src + 4));
    uint4 u;
    u.x = pk2(v0.x, v0.y); u.y = pk2(v0.z, v0.w);
    u.z = pk2(v1.x, v1.y); u.w = pk2(v1.z, v1.w);
    *reinterpret_cast<uint4*>(&imgbfP[gid * 8]) = u;
}

// ---- Wi [D][A] f32 -> Bp fragment-packed bf16: [nf = col/16][ks][lane][8]
__global__ void bpack(const float* __restrict__ Wi, unsigned short* __restrict__ Bp) {
    int nf = blockIdx.x, ks = blockIdx.y, l = threadIdx.x;
    int col = nf * 16 + (l & 15);
    int k0  = ks * 32 + (l >> 4) * 8;
    unsigned short o[8];
    #pragma unroll
    for (int e = 0; e < 8; ++e) o[e] = f2bf(Wi[(size_t)(k0 + e) * A_ + col]);
    *reinterpret_cast<uint4*>(&Bp[(((size_t)nf * 32 + ks) * 64 + l) * 8]) =
        *reinterpret_cast<const uint4*>(o);
}

// ---- qe partials: qep[ds][b][a] = sum over d in ds-slice of q[b][d]*W[d][a]
__global__ __launch_bounds__(256)
void qproj(const float* __restrict__ q, const float* __restrict__ W,
           float* __restrict__ qep) {
    __shared__ float qs[8][256];
    int b0 = blockIdx.x * 8;
    int a  = blockIdx.y * 256 + threadIdx.x;
    int ds = blockIdx.z;
    for (int i = threadIdx.x; i < 8 * 256; i += 256)
        qs[i >> 8][i & 255] = q[(b0 + (i >> 8)) * D_ + ds * 256 + (i & 255)];
    __syncthreads();
    float acc[8] = {0.f, 0.f, 0.f, 0.f, 0.f, 0.f, 0.f, 0.f};
    #pragma unroll 8
    for (int dd = 0; dd < 256; ++dd) {
        float w = W[(size_t)(ds * 256 + dd) * A_ + a];
        #pragma unroll
        for (int j = 0; j < 8; ++j) acc[j] += qs[j][dd] * w;
    }
    #pragma unroll
    for (int j = 0; j < 8; ++j)
        qep[((size_t)ds * B_ + b0 + j) * A_ + a] = acc[j];
}

// ---- fused score partials: scp[nb][row] = sum over cols nb*128..+127 of
//      Ws[col]*tanh(qe[b][col] + (img[row]@Wi)[col])
// 128x128 tile, 8 waves of 32x64 (acc=32 VGPR), 512 thr, 16 waves/CU target.
#define MT 128

__global__ __launch_bounds__(512, 4)
void score_kernel(const unsigned short* __restrict__ imgbfP,
                  const unsigned short* __restrict__ Bp,
                  const float* __restrict__ qep,   // [4][B][A] partials
                  const float* __restrict__ qbias, // [A]
                  const float* __restrict__ Ws,
                  float* __restrict__ scp)
{
    __shared__ __align__(16) unsigned short Asm[8 * 2 * 64 * 8];   // 16 KB
    __shared__ __align__(16) unsigned short Bsm[8 * 2 * 64 * 8];   // 16 KB
    __shared__ float ws_s[MT];
    __shared__ float qe_s[2][MT];
    __shared__ float score_s[MT];

    const int tid  = threadIdx.x;
    const int lane = tid & 63;
    const int wave = tid >> 6;          // 0..7
    const int wm   = wave >> 1;         // 0..3 : 32-row slice
    const int wn   = wave & 1;          // 0..1 : 64-col slice

    const int orig = blockIdx.x;
    const int xcd  = orig & 7;
    const int j    = orig >> 3;
    const int rowpanel = xcd * 98 + (j >> 2);
    const int nb       = j & 3;

    const long row0   = (long)rowpanel * MT;
    const long rfrag0 = row0 >> 4;
    const int  b0     = (int)(row0 / S_);
    const long b0s    = (long)b0 * S_;

    if (tid < MT) {
        int col = nb * MT + tid;
        ws_s[tid] = Ws[col];
        float bb  = qbias[col];
        float s0 = qep[((size_t)0 * B_ + b0) * A_ + col]
                 + qep[((size_t)1 * B_ + b0) * A_ + col]
                 + qep[((size_t)2 * B_ + b0) * A_ + col]
                 + qep[((size_t)3 * B_ + b0) * A_ + col];
        qe_s[0][tid] = s0 + bb;
        float s1 = 0.f;
        if (b0 + 1 < B_) {
            s1 = qep[((size_t)0 * B_ + b0 + 1) * A_ + col]
               + qep[((size_t)1 * B_ + b0 + 1) * A_ + col]
               + qep[((size_t)2 * B_ + b0 + 1) * A_ + col]
               + qep[((size_t)3 * B_ + b0 + 1) * A_ + col] + bb;
        }
        qe_s[1][tid] = s1;
        score_s[tid] = 0.f;
    }

    f32x4 acc[2][4];
    #pragma unroll
    for (int m = 0; m < 2; ++m)
        #pragma unroll
        for (int n = 0; n < 4; ++n) acc[m][n] = (f32x4)0.f;

    // 32 chunks of 1 KB per K-step (A:16, B:16); 8 waves x 4 chunks
    auto STAGE = [&](int t) {
        #pragma unroll
        for (int c = 0; c < 4; ++c) {
            int q = wave * 4 + c;        // 0..31
            if (q < 16) {
                int rf = q >> 1, kk = q & 1;
                const unsigned short* ga =
                    imgbfP + (((size_t)(rfrag0 + rf) * 32 + (t * 2 + kk)) * 64 + lane) * 8;
                __builtin_amdgcn_global_load_lds(
                    (const __attribute__((address_space(1))) void*)ga,
                    (__attribute__((address_space(3))) void*)&Asm[((rf * 2 + kk) * 64) * 8],
                    16, 0, 0);
            } else {
                int nf = (q - 16) >> 1, kk = q & 1;
                const unsigned short* gb =
                    Bp + (((size_t)(nb * 8 + nf) * 32 + (t * 2 + kk)) * 64 + lane) * 8;
                __builtin_amdgcn_global_load_lds(
                    (const __attribute__((address_space(1))) void*)gb,
                    (__attribute__((address_space(3))) void*)&Bsm[((nf * 2 + kk) * 64) * 8],
                    16, 0, 0);
            }
        }
    };

    for (int t = 0; t < 16; ++t) {
        STAGE(t);
        __syncthreads();
        #pragma unroll
        for (int kk = 0; kk < 2; ++kk) {
            bf16x8_t afr[2], bfr[4];
            #pragma unroll
            for (int m = 0; m < 2; ++m)
                afr[m] = *reinterpret_cast<const bf16x8_t*>(
                    &Asm[(((wm * 2 + m) * 2 + kk) * 64 + lane) * 8]);
            #pragma unroll
            for (int n = 0; n < 4; ++n)
                bfr[n] = *reinterpret_cast<const bf16x8_t*>(
                    &Bsm[(((wn * 4 + n) * 2 + kk) * 64 + lane) * 8]);
            #pragma unroll
            for (int m = 0; m < 2; ++m)
                #pragma unroll
                for (int n = 0; n < 4; ++n)
                    acc[m][n] = __builtin_amdgcn_mfma_f32_16x16x32_bf16(
                        afr[m], bfr[n], acc[m][n], 0, 0, 0);
        }
        __syncthreads();
    }

    // epilogue: sum over this wave's 64 cols; 2 waves (wn=0,1) share rows -> atomic
    #pragma unroll
    for (int m = 0; m < 2; ++m) {
        #pragma unroll
        for (int r = 0; r < 4; ++r) {
            int rowl = wm * 32 + m * 16 + ((lane >> 4) << 2) + r;
            int sel  = ((row0 + rowl - b0s) >= S_) ? 1 : 0;
            float v = 0.f;
            #pragma unroll
            for (int n = 0; n < 4; ++n) {
                int coll = wn * 64 + n * 16 + (lane & 15);
                float x = acc[m][n][r] + qe_s[sel][coll];
                float e = __expf(2.f * x);
                v += ws_s[coll] * (1.f - 2.f * __builtin_amdgcn_rcpf(e + 1.f));
            }
            v += __shfl_xor(v, 1);
            v += __shfl_xor(v, 2);
            v += __shfl_xor(v, 4);
            v += __shfl_xor(v, 8);
            if ((lane & 15) == 0) atomicAdd(&score_s[rowl], v);
        }
    }
    __syncthreads();
    if (tid < MT) scp[(size_t)nb * NROW + row0 + tid] = score_s[tid];
}

// ---- fused: sum 4 partials -> softmax(196) -> pool ks-quadrant -> +residual
__global__ __launch_bounds__(256)
void softpool(const float* __restrict__ scp, const unsigned short* __restrict__ imgbfP,
              const float* __restrict__ qin, float* __restrict__ uout) {
    __shared__ float pp[208];
    __shared__ float red1[4], red2[4];
    int b = blockIdx.x, quad = blockIdx.y, t = threadIdx.x;
    int lane = t & 63, w = t >> 6;

    float v = -1e30f;
    if (t < S_) {
        size_t r = (size_t)b * S_ + t;
        v = scp[r] + scp[(size_t)NROW + r] + scp[2 * (size_t)NROW + r] + scp[3 * (size_t)NROW + r];
    }
    float m = v;
    #pragma unroll
    for (int o = 1; o < 64; o <<= 1) m = fmaxf(m, __shfl_xor(m, o));
    if (lane == 0) red1[w] = m;
    __syncthreads();
    m = fmaxf(fmaxf(red1[0], red1[1]), fmaxf(red1[2], red1[3]));
    float e = (t < S_) ? __expf(v - m) : 0.f;
    float s = e;
    #pragma unroll
    for (int o = 1; o < 64; o <<= 1) s += __shfl_xor(s, o);
    if (lane == 0) red2[w] = s;
    __syncthreads();
    s = (red2[0] + red2[1]) + (red2[2] + red2[3]);

    const long rfrag0 = ((long)b * S_) >> 4;
    const int  off    = (int)(((long)b * S_) & 15);   // 0,4,8,12 ; off+196 <= 208
    if (t < 208) pp[t] = 0.f;
    __syncthreads();
    if (t < S_) pp[t + off] = e / s;
    __syncthreads();

    const int g  = lane >> 4;
    const int rl = lane & 15;
    #pragma unroll
    for (int ki = 0; ki < 2; ++ki) {
        int ks = quad * 8 + w + ki * 4;
        float a[8] = {0.f, 0.f, 0.f, 0.f, 0.f, 0.f, 0.f, 0.f};
        #pragma unroll
        for (int rf = 0; rf < 13; ++rf) {
            const unsigned short* p16 =
                imgbfP + (((size_t)(rfrag0 + rf) * 32 + ks) * 64 + lane) * 8;
            uint4 u = *reinterpret_cast<const uint4*>(p16);
            float p = pp[rf * 16 + rl];
            const unsigned short* hs = reinterpret_cast<const unsigned short*>(&u);
            #pragma unroll
            for (int e2 = 0; e2 < 8; ++e2) a[e2] += p * bf2f(hs[e2]);
        }
        #pragma unroll
        for (int e2 = 0; e2 < 8; ++e2) {
            a[e2] += __shfl_xor(a[e2], 1);
            a[e2] += __shfl_xor(a[e2], 2);
            a[e2] += __shfl_xor(a[e2], 4);
            a[e2] += __shfl_xor(a[e2], 8);
        }
        if (rl == 0) {
            int d = ks * 32 + g * 8;
            const float* qb = &qin[(size_t)b * D_ + d];
            float* ob = &uout[(size_t)b * D_ + d];
            float4 q0 = *reinterpret_cast<const float4*>(qb);
            float4 q1 = *reinterpret_cast<const float4*>(qb + 4);
            float4 o0 = make_float4(q0.x + a[0], q0.y + a[1], q0.z + a[2], q0.w + a[3]);
            float4 o1 = make_float4(q1.x + a[4], q1.y + a[5], q1.z + a[6], q1.w + a[7]);
            *reinterpret_cast<float4*>(ob)     = o0;
            *reinterpret_cast<float4*>(ob + 4) = o1;
        }
    }
}

// ---- fcout partials: fcp[ds][b][o] over d-halves; grid (B/16, 4 ochunks, 2 ds)
__global__ __launch_bounds__(256)
void fcout(const float* __restrict__ u, const float* __restrict__ W,
           float* __restrict__ fcp) {
    __shared__ float us[16][512];
    int b0 = blockIdx.x * 16;
    int o  = blockIdx.y * 256 + threadIdx.x;
    int ds = blockIdx.z;
    for (int i = threadIdx.x; i < 16 * 512; i += 256)
        us[i >> 9][i & 511] = u[(b0 + (i >> 9)) * D_ + ds * 512 + (i & 511)];
    __syncthreads();
    if (o < O_) {
        float acc[16];
        #pragma unroll
        for (int j = 0; j < 16; ++j) acc[j] = 0.f;
        #pragma unroll 4
        for (int dd = 0; dd < 512; ++dd) {
            float w = W[(size_t)(ds * 512 + dd) * O_ + o];
            #pragma unroll
            for (int j = 0; j < 16; ++j) acc[j] += us[j][dd] * w;
        }
        #pragma unroll
        for (int j = 0; j < 16; ++j)
            fcp[((size_t)ds * B_ + b0 + j) * O_ + o] = acc[j];
    }
}

// ---- out = fcp0 + fcp1 + bias
__global__ __launch_bounds__(256)
void fcred(const float* __restrict__ fcp, const float* __restrict__ bias,
           float* __restrict__ out) {
    int i = blockIdx.x * 256 + threadIdx.x;
    if (i < B_ * O_)
        out[i] = fcp[i] + fcp[(size_t)B_ * O_ + i] + bias[i % O_];
}

extern "C" void kernel_launch(void* const* d_in, const int* in_sizes, int n_in,
                              void* d_out, int out_size, void* d_ws, size_t ws_size,
                              hipStream_t stream) {
    (void)in_sizes; (void)n_in; (void)out_size; (void)ws_size;
    const float* ques = (const float*)d_in[0];
    const float* img  = (const float*)d_in[1];
    const float* W11  = (const float*)d_in[2];
    const float* b11  = (const float*)d_in[3];
    const float* W12  = (const float*)d_in[4];
    const float* W13  = (const float*)d_in[5];
    // d_in[6] = b13: softmax-invariant, unused
    const float* W21  = (const float*)d_in[7];
    const float* b21  = (const float*)d_in[8];
    const float* W22  = (const float*)d_in[9];
    const float* W23  = (const float*)d_in[10];
    // d_in[11] = b23: softmax-invariant, unused
    const float* Wfc  = (const float*)d_in[12];
    const float* bfc  = (const float*)d_in[13];
    float* out = (float*)d_out;

    char* ws = (char*)d_ws;
    unsigned short* imgbfP = (unsigned short*)ws; ws += (size_t)NROW * D_ * 2;  // 205.5 MB
    unsigned short* Bp1 = (unsigned short*)ws; ws += (size_t)A_ * D_ * 2;       // 1 MB
    unsigned short* Bp2 = (unsigned short*)ws; ws += (size_t)A_ * D_ * 2;       // 1 MB
    float* qep = (float*)ws; ws += (size_t)4 * B_ * A_ * 4;                     // 4 MB
    float* scp = (float*)ws; ws += (size_t)4 * NROW * 4;                        // 1.6 MB
    float* u1  = (float*)ws; ws += (size_t)B_ * D_ * 4;                         // 2 MB
    float* u2  = (float*)ws; ws += (size_t)B_ * D_ * 4;                         // 2 MB
    float* fcp = (float*)ws;                                                    // 4 MB

    const int nscore = (NROW / MT) * 4;   // 3136

    img2bf<<<dim3(NROW / 16 * 32 * 64 / 256), 256, 0, stream>>>(img, imgbfP);

    // hop 1
    bpack<<<dim3(32, 32), 64, 0, stream>>>(W12, Bp1);
    qproj<<<dim3(B_ / 8, A_ / 256, 4), 256, 0, stream>>>(ques, W11, qep);
    score_kernel<<<dim3(nscore), 512, 0, stream>>>(imgbfP, Bp1, qep, b11, W13, scp);
    softpool<<<dim3(B_, 4), 256, 0, stream>>>(scp, imgbfP, ques, u1);

    // hop 2
    bpack<<<dim3(32, 32), 64, 0, stream>>>(W22, Bp2);
    qproj<<<dim3(B_ / 8, A_ / 256, 4), 256, 0, stream>>>(u1, W21, qep);
    score_kernel<<<dim3(nscore), 512, 0, stream>>>(imgbfP, Bp2, qep, b21, W23, scp);
    softpool<<<dim3(B_, 4), 256, 0, stream>>>(scp, imgbfP, u1, u2);

    // final FC
    fcout<<<dim3(B_ / 16, (O_ + 255) / 256, 2), 256, 0, stream>>>(u2, Wfc, fcp);
    fcred<<<dim3((B_ * O_ + 255) / 256), 256, 0, stream>>>(fcp, bfc, out);
}

// Round 17
// 516.771 us; speedup vs baseline: 1.0391x; 1.0391x over previous
//
#include <hip/hip_runtime.h>
#include <hip/hip_bf16.h>

#define B_  512
#define S_  196
#define D_  1024
#define A_  512
#define O_  1000
#define NROW (B_ * S_)   // 100352 = 784 * 128

typedef __attribute__((ext_vector_type(8))) __bf16 bf16x8_t;
typedef __attribute__((ext_vector_type(4))) float f32x4;
typedef __attribute__((ext_vector_type(4))) float f32x4v;

__device__ __forceinline__ unsigned short f2bf(float f) {
    union { float f; unsigned u; } v; v.f = f;
    unsigned r = v.u + 0x7FFFu + ((v.u >> 16) & 1u);   // RNE
    return (unsigned short)(r >> 16);
}
__device__ __forceinline__ unsigned pk2(float lo, float hi) {
    return (unsigned)f2bf(lo) | ((unsigned)f2bf(hi) << 16);
}
__device__ __forceinline__ float bf2f(unsigned short h) {
    union { unsigned u; float f; } v; v.u = ((unsigned)h) << 16;
    return v.f;
}

// ---- img [NROW][1024] f32 -> imgbfP fragment-packed bf16:
//      [rfrag = row/16][ks = k/32][lane][8]  where lane = (row&15) + 16*((k&31)/8)
__global__ void img2bf(const float* __restrict__ img, unsigned short* __restrict__ imgbfP) {
    size_t gid = (size_t)blockIdx.x * 256 + threadIdx.x;
    int    lane  = (int)(gid & 63);
    size_t chunk = gid >> 6;             // (rfrag*32 + ks)
    int    ks    = (int)(chunk & 31);
    size_t rfrag = chunk >> 5;
    int row = (int)(rfrag * 16 + (lane & 15));
    int k0  = ks * 32 + (lane >> 4) * 8;
    const float* src = img + (size_t)row * D_ + k0;
    f32x4v v0 = __builtin_nontemporal_load(reinterpret_cast<const f32x4v*>(src));
    f32x4v v1 = __builtin_nontemporal_load(reinterpret_cast<const f32x4v*>(src + 4));
    uint4 u;
    u.x = pk2(v0.x, v0.y); u.y = pk2(v0.z, v0.w);
    u.z = pk2(v1.x, v1.y); u.w = pk2(v1.z, v1.w);
    *reinterpret_cast<uint4*>(&imgbfP[gid * 8]) = u;
}

// ---- Wi [D][A] f32 -> Bp fragment-packed bf16: [nf = col/16][ks][lane][8]
__global__ void bpack(const float* __restrict__ Wi, unsigned short* __restrict__ Bp) {
    int nf = blockIdx.x, ks = blockIdx.y, l = threadIdx.x;
    int col = nf * 16 + (l & 15);
    int k0  = ks * 32 + (l >> 4) * 8;
    unsigned short o[8];
    #pragma unroll
    for (int e = 0; e < 8; ++e) o[e] = f2bf(Wi[(size_t)(k0 + e) * A_ + col]);
    *reinterpret_cast<uint4*>(&Bp[(((size_t)nf * 32 + ks) * 64 + l) * 8]) =
        *reinterpret_cast<const uint4*>(o);
}

// ---- qe partials: qep[ds][b][a] = sum over d in ds-slice of q[b][d]*W[d][a]
__global__ __launch_bounds__(256)
void qproj(const float* __restrict__ q, const float* __restrict__ W,
           float* __restrict__ qep) {
    __shared__ float qs[8][256];
    int b0 = blockIdx.x * 8;
    int a  = blockIdx.y * 256 + threadIdx.x;
    int ds = blockIdx.z;
    for (int i = threadIdx.x; i < 8 * 256; i += 256)
        qs[i >> 8][i & 255] = q[(b0 + (i >> 8)) * D_ + ds * 256 + (i & 255)];
    __syncthreads();
    float acc[8] = {0.f, 0.f, 0.f, 0.f, 0.f, 0.f, 0.f, 0.f};
    #pragma unroll 8
    for (int dd = 0; dd < 256; ++dd) {
        float w = W[(size_t)(ds * 256 + dd) * A_ + a];
        #pragma unroll
        for (int j = 0; j < 8; ++j) acc[j] += qs[j][dd] * w;
    }
    #pragma unroll
    for (int j = 0; j < 8; ++j)
        qep[((size_t)ds * B_ + b0 + j) * A_ + a] = acc[j];
}

// ---- fused score partials (R8-proven structure): scp[nb][row] =
//      sum over cols nb*128..+127 of Ws[col]*tanh(qe[b][col] + (img[row]@Wi)[col])
#define MT 128

__global__ __launch_bounds__(256, 3)
void score_kernel(const unsigned short* __restrict__ imgbfP,
                  const unsigned short* __restrict__ Bp,
                  const float* __restrict__ qep,   // [4][B][A] partials
                  const float* __restrict__ qbias, // [A]
                  const float* __restrict__ Ws,
                  float* __restrict__ scp)
{
    __shared__ __align__(16) unsigned short Asm[8 * 2 * 64 * 8];   // 16 KB
    __shared__ __align__(16) unsigned short Bsm[8 * 2 * 64 * 8];   // 16 KB
    __shared__ float ws_s[MT];
    __shared__ float qe_s[2][MT];
    __shared__ float score_s[MT];

    const int tid  = threadIdx.x;
    const int lane = tid & 63;
    const int wave = tid >> 6;          // 0..3
    const int wm   = wave >> 1;
    const int wn   = wave & 1;

    const int orig = blockIdx.x;
    const int xcd  = orig & 7;
    const int j    = orig >> 3;
    const int rowpanel = xcd * 98 + (j >> 2);
    const int nb       = j & 3;

    const long row0   = (long)rowpanel * MT;
    const long rfrag0 = row0 >> 4;
    const int  b0     = (int)(row0 / S_);
    const long b0s    = (long)b0 * S_;

    if (tid < MT) {
        int col = nb * MT + tid;
        ws_s[tid] = Ws[col];
        float bb  = qbias[col];
        float s0 = qep[((size_t)0 * B_ + b0) * A_ + col]
                 + qep[((size_t)1 * B_ + b0) * A_ + col]
                 + qep[((size_t)2 * B_ + b0) * A_ + col]
                 + qep[((size_t)3 * B_ + b0) * A_ + col];
        qe_s[0][tid] = s0 + bb;
        float s1 = 0.f;
        if (b0 + 1 < B_) {
            s1 = qep[((size_t)0 * B_ + b0 + 1) * A_ + col]
               + qep[((size_t)1 * B_ + b0 + 1) * A_ + col]
               + qep[((size_t)2 * B_ + b0 + 1) * A_ + col]
               + qep[((size_t)3 * B_ + b0 + 1) * A_ + col] + bb;
        }
        qe_s[1][tid] = s1;
        score_s[tid] = 0.f;
    }

    f32x4 acc[4][4];
    #pragma unroll
    for (int m = 0; m < 4; ++m)
        #pragma unroll
        for (int n = 0; n < 4; ++n) acc[m][n] = (f32x4)0.f;

    auto STAGE = [&](int t) {
        #pragma unroll
        for (int c = 0; c < 4; ++c) {
            int q  = wave * 4 + c;
            int rf = q >> 1, kk = q & 1;
            const unsigned short* ga =
                imgbfP + (((size_t)(rfrag0 + rf) * 32 + (t * 2 + kk)) * 64 + lane) * 8;
            __builtin_amdgcn_global_load_lds(
                (const __attribute__((address_space(1))) void*)ga,
                (__attribute__((address_space(3))) void*)&Asm[((rf * 2 + kk) * 64) * 8],
                16, 0, 0);
            const unsigned short* gb =
                Bp + (((size_t)(nb * 8 + rf) * 32 + (t * 2 + kk)) * 64 + lane) * 8;
            __builtin_amdgcn_global_load_lds(
                (const __attribute__((address_space(1))) void*)gb,
                (__attribute__((address_space(3))) void*)&Bsm[((rf * 2 + kk) * 64) * 8],
                16, 0, 0);
        }
    };

    for (int t = 0; t < 16; ++t) {
        STAGE(t);
        __syncthreads();
        #pragma unroll
        for (int kk = 0; kk < 2; ++kk) {
            bf16x8_t afr[4], bfr[4];
            #pragma unroll
            for (int m = 0; m < 4; ++m)
                afr[m] = *reinterpret_cast<const bf16x8_t*>(
                    &Asm[(((wm * 4 + m) * 2 + kk) * 64 + lane) * 8]);
            #pragma unroll
            for (int n = 0; n < 4; ++n)
                bfr[n] = *reinterpret_cast<const bf16x8_t*>(
                    &Bsm[(((wn * 4 + n) * 2 + kk) * 64 + lane) * 8]);
            #pragma unroll
            for (int m = 0; m < 4; ++m)
                #pragma unroll
                for (int n = 0; n < 4; ++n)
                    acc[m][n] = __builtin_amdgcn_mfma_f32_16x16x32_bf16(
                        afr[m], bfr[n], acc[m][n], 0, 0, 0);
        }
        __syncthreads();
    }

    #pragma unroll
    for (int m = 0; m < 4; ++m) {
        #pragma unroll
        for (int r = 0; r < 4; ++r) {
            int rowl = wm * 64 + m * 16 + ((lane >> 4) << 2) + r;
            int sel  = ((row0 + rowl - b0s) >= S_) ? 1 : 0;
            float v = 0.f;
            #pragma unroll
            for (int n = 0; n < 4; ++n) {
                int coll = wn * 64 + n * 16 + (lane & 15);
                float x = acc[m][n][r] + qe_s[sel][coll];
                float e = __expf(2.f * x);
                v += ws_s[coll] * (1.f - 2.f * __builtin_amdgcn_rcpf(e + 1.f));
            }
            v += __shfl_xor(v, 1);
            v += __shfl_xor(v, 2);
            v += __shfl_xor(v, 4);
            v += __shfl_xor(v, 8);
            if ((lane & 15) == 0) atomicAdd(&score_s[rowl], v);
        }
    }
    __syncthreads();
    if (tid < MT) scp[(size_t)nb * NROW + row0 + tid] = score_s[tid];
}

// ---- fused: sum 4 partials -> softmax(196) -> pool ks-quadrant -> +residual
//      grid (B, 4 quadrants), 2048 blocks
__global__ __launch_bounds__(256)
void softpool(const float* __restrict__ scp, const unsigned short* __restrict__ imgbfP,
              const float* __restrict__ qin, float* __restrict__ uout) {
    __shared__ float pp[208];
    __shared__ float red1[4], red2[4];
    int b = blockIdx.x, quad = blockIdx.y, t = threadIdx.x;
    int lane = t & 63, w = t >> 6;

    float v = -1e30f;
    if (t < S_) {
        size_t r = (size_t)b * S_ + t;
        v = scp[r] + scp[(size_t)NROW + r] + scp[2 * (size_t)NROW + r] + scp[3 * (size_t)NROW + r];
    }
    float m = v;
    #pragma unroll
    for (int o = 1; o < 64; o <<= 1) m = fmaxf(m, __shfl_xor(m, o));
    if (lane == 0) red1[w] = m;
    __syncthreads();
    m = fmaxf(fmaxf(red1[0], red1[1]), fmaxf(red1[2], red1[3]));
    float e = (t < S_) ? __expf(v - m) : 0.f;
    float s = e;
    #pragma unroll
    for (int o = 1; o < 64; o <<= 1) s += __shfl_xor(s, o);
    if (lane == 0) red2[w] = s;
    __syncthreads();
    s = (red2[0] + red2[1]) + (red2[2] + red2[3]);

    const long rfrag0 = ((long)b * S_) >> 4;
    const int  off    = (int)(((long)b * S_) & 15);   // 0,4,8,12 ; off+196 <= 208
    if (t < 208) pp[t] = 0.f;
    __syncthreads();
    if (t < S_) pp[t + off] = e / s;
    __syncthreads();

    const int g  = lane >> 4;
    const int rl = lane & 15;
    #pragma unroll
    for (int ki = 0; ki < 2; ++ki) {
        int ks = quad * 8 + w + ki * 4;
        float a[8] = {0.f, 0.f, 0.f, 0.f, 0.f, 0.f, 0.f, 0.f};
        #pragma unroll
        for (int rf = 0; rf < 13; ++rf) {
            const unsigned short* p16 =
                imgbfP + (((size_t)(rfrag0 + rf) * 32 + ks) * 64 + lane) * 8;
            uint4 u = *reinterpret_cast<const uint4*>(p16);
            float p = pp[rf * 16 + rl];
            const unsigned short* hs = reinterpret_cast<const unsigned short*>(&u);
            #pragma unroll
            for (int e2 = 0; e2 < 8; ++e2) a[e2] += p * bf2f(hs[e2]);
        }
        #pragma unroll
        for (int e2 = 0; e2 < 8; ++e2) {
            a[e2] += __shfl_xor(a[e2], 1);
            a[e2] += __shfl_xor(a[e2], 2);
            a[e2] += __shfl_xor(a[e2], 4);
            a[e2] += __shfl_xor(a[e2], 8);
        }
        if (rl == 0) {
            int d = ks * 32 + g * 8;
            const float* qb = &qin[(size_t)b * D_ + d];
            float* ob = &uout[(size_t)b * D_ + d];
            float4 q0 = *reinterpret_cast<const float4*>(qb);
            float4 q1 = *reinterpret_cast<const float4*>(qb + 4);
            float4 o0 = make_float4(q0.x + a[0], q0.y + a[1], q0.z + a[2], q0.w + a[3]);
            float4 o1 = make_float4(q1.x + a[4], q1.y + a[5], q1.z + a[6], q1.w + a[7]);
            *reinterpret_cast<float4*>(ob)     = o0;
            *reinterpret_cast<float4*>(ob + 4) = o1;
        }
    }
}

// ---- fcout partials: fcp[ds][b][o] over d-halves; grid (B/16, 4 ochunks, 2 ds)
__global__ __launch_bounds__(256)
void fcout(const float* __restrict__ u, const float* __restrict__ W,
           float* __restrict__ fcp) {
    __shared__ float us[16][512];
    int b0 = blockIdx.x * 16;
    int o  = blockIdx.y * 256 + threadIdx.x;
    int ds = blockIdx.z;
    for (int i = threadIdx.x; i < 16 * 512; i += 256)
        us[i >> 9][i & 511] = u[(b0 + (i >> 9)) * D_ + ds * 512 + (i & 511)];
    __syncthreads();
    if (o < O_) {
        float acc[16];
        #pragma unroll
        for (int j = 0; j < 16; ++j) acc[j] = 0.f;
        #pragma unroll 4
        for (int dd = 0; dd < 512; ++dd) {
            float w = W[(size_t)(ds * 512 + dd) * O_ + o];
            #pragma unroll
            for (int j = 0; j < 16; ++j) acc[j] += us[j][dd] * w;
        }
        #pragma unroll
        for (int j = 0; j < 16; ++j)
            fcp[((size_t)ds * B_ + b0 + j) * O_ + o] = acc[j];
    }
}

// ---- out = fcp0 + fcp1 + bias
__global__ __launch_bounds__(256)
void fcred(const float* __restrict__ fcp, const float* __restrict__ bias,
           float* __restrict__ out) {
    int i = blockIdx.x * 256 + threadIdx.x;
    if (i < B_ * O_)
        out[i] = fcp[i] + fcp[(size_t)B_ * O_ + i] + bias[i % O_];
}

extern "C" void kernel_launch(void* const* d_in, const int* in_sizes, int n_in,
                              void* d_out, int out_size, void* d_ws, size_t ws_size,
                              hipStream_t stream) {
    (void)in_sizes; (void)n_in; (void)out_size; (void)ws_size;
    const float* ques = (const float*)d_in[0];
    const float* img  = (const float*)d_in[1];
    const float* W11  = (const float*)d_in[2];
    const float* b11  = (const float*)d_in[3];
    const float* W12  = (const float*)d_in[4];
    const float* W13  = (const float*)d_in[5];
    // d_in[6] = b13: softmax-invariant, unused
    const float* W21  = (const float*)d_in[7];
    const float* b21  = (const float*)d_in[8];
    const float* W22  = (const float*)d_in[9];
    const float* W23  = (const float*)d_in[10];
    // d_in[11] = b23: softmax-invariant, unused
    const float* Wfc  = (const float*)d_in[12];
    const float* bfc  = (const float*)d_in[13];
    float* out = (float*)d_out;

    char* ws = (char*)d_ws;
    unsigned short* imgbfP = (unsigned short*)ws; ws += (size_t)NROW * D_ * 2;  // 205.5 MB
    unsigned short* Bp1 = (unsigned short*)ws; ws += (size_t)A_ * D_ * 2;       // 1 MB
    unsigned short* Bp2 = (unsigned short*)ws; ws += (size_t)A_ * D_ * 2;       // 1 MB
    float* qep = (float*)ws; ws += (size_t)4 * B_ * A_ * 4;                     // 4 MB
    float* scp = (float*)ws; ws += (size_t)4 * NROW * 4;                        // 1.6 MB
    float* u1  = (float*)ws; ws += (size_t)B_ * D_ * 4;                         // 2 MB
    float* u2  = (float*)ws; ws += (size_t)B_ * D_ * 4;                         // 2 MB
    float* fcp = (float*)ws;                                                    // 4 MB

    const int nscore = (NROW / MT) * 4;   // 3136

    img2bf<<<dim3(NROW / 16 * 32 * 64 / 256), 256, 0, stream>>>(img, imgbfP);

    // hop 1
    bpack<<<dim3(32, 32), 64, 0, stream>>>(W12, Bp1);
    qproj<<<dim3(B_ / 8, A_ / 256, 4), 256, 0, stream>>>(ques, W11, qep);
    score_kernel<<<dim3(nscore), 256, 0, stream>>>(imgbfP, Bp1, qep, b11, W13, scp);
    softpool<<<dim3(B_, 4), 256, 0, stream>>>(scp, imgbfP, ques, u1);

    // hop 2
    bpack<<<dim3(32, 32), 64, 0, stream>>>(W22, Bp2);
    qproj<<<dim3(B_ / 8, A_ / 256, 4), 256, 0, stream>>>(u1, W21, qep);
    score_kernel<<<dim3(nscore), 256, 0, stream>>>(imgbfP, Bp2, qep, b21, W23, scp);
    softpool<<<dim3(B_, 4), 256, 0, stream>>>(scp, imgbfP, u1, u2);

    // final FC
    fcout<<<dim3(B_ / 16, (O_ + 255) / 256, 2), 256, 0, stream>>>(u2, Wfc, fcp);
    fcred<<<dim3((B_ * O_ + 255) / 256), 256, 0, stream>>>(fcp, bfc, out);
}